// Round 7
// baseline (34024.200 us; speedup 1.0000x reference)
//
#include <hip/hip_runtime.h>
#include <stdint.h>
#include <stddef.h>

typedef __bf16 bf16x8 __attribute__((ext_vector_type(8)));
typedef float f32x4 __attribute__((ext_vector_type(4)));
typedef uint32_t u32x4v __attribute__((ext_vector_type(4)));

#define MFMA16(a, b, c) __builtin_amdgcn_mfma_f32_16x16x32_bf16((a), (b), (c), 0, 0, 0)

// problem dims
#define TSTEPS 1024
#define NDIM   64
#define NKC    10     // gate K-chunks: 0,1 = noise(64); 2..9 = h chunks of 32
#define NGT    64
#define MB     16
#define GROUPS 32
#define SLICES 8

// workspace layout (bytes)
#define GOFF    ((size_t)0)
#define GBYTES  ((size_t)NGT * NKC * 1024)       // 655360
#define W1OFF   (GOFF + GBYTES)
#define W1BYTES ((size_t)16 * 8 * 1024)          // 131072
#define BOFF    (W1OFF + W1BYTES)                // 1024 f32 reordered gate bias
#define XOFF    (BOFF + 4096)                    // ids (1KB) + payF (1MB) + payS (1MB)
#define IDSB    ((size_t)1024)
#define PAYB    ((size_t)256 * 2 * 512 * 4)      // 1 MiB per flavor
#define WSNEED  (XOFF + IDSB + 2 * PAYB)

__device__ __forceinline__ uint16_t f2bf(float f) {
    union { float f; uint32_t u; } v; v.f = f;
    return (uint16_t)((v.u + 0x7FFFu + ((v.u >> 16) & 1u)) >> 16);  // RNE
}
__device__ __forceinline__ float fsig(float x) { return 1.0f / (1.0f + __expf(-x)); }
__device__ __forceinline__ float ftanh(float x) { return 2.0f / (1.0f + __expf(-2.0f * x)) - 1.0f; }

__device__ __forceinline__ void bar_lgkm() {
    asm volatile("s_waitcnt lgkmcnt(0)" ::: "memory");
    __builtin_amdgcn_s_barrier();
    asm volatile("" ::: "memory");
}

__device__ __forceinline__ bool tagpair_ok(u32x4v A, u32x4v B, uint32_t tg) {
    return ((A[0] >> 16) == tg) & ((A[1] >> 16) == tg) & ((A[2] >> 16) == tg) & ((A[3] >> 16) == tg)
         & ((B[0] >> 16) == tg) & ((B[1] >> 16) == tg) & ((B[2] >> 16) == tg) & ((B[3] >> 16) == tg);
}
__device__ __forceinline__ bf16x8 repack(u32x4v A, u32x4v B) {
    uint4 r;
    r.x = (A[0] & 0xffffu) | (A[1] << 16);
    r.y = (A[2] & 0xffffu) | (A[3] << 16);
    r.z = (B[0] & 0xffffu) | (B[1] << 16);
    r.w = (B[2] & 0xffffu) | (B[3] << 16);
    return __builtin_bit_cast(bf16x8, r);
}
__device__ __forceinline__ void spoll2(const uint32_t* p, u32x4v& A, u32x4v& B) {
    A[0] = __hip_atomic_load(p + 0, __ATOMIC_RELAXED, __HIP_MEMORY_SCOPE_AGENT);
    A[1] = __hip_atomic_load(p + 1, __ATOMIC_RELAXED, __HIP_MEMORY_SCOPE_AGENT);
    A[2] = __hip_atomic_load(p + 2, __ATOMIC_RELAXED, __HIP_MEMORY_SCOPE_AGENT);
    A[3] = __hip_atomic_load(p + 3, __ATOMIC_RELAXED, __HIP_MEMORY_SCOPE_AGENT);
    B[0] = __hip_atomic_load(p + 4, __ATOMIC_RELAXED, __HIP_MEMORY_SCOPE_AGENT);
    B[1] = __hip_atomic_load(p + 5, __ATOMIC_RELAXED, __HIP_MEMORY_SCOPE_AGENT);
    B[2] = __hip_atomic_load(p + 6, __ATOMIC_RELAXED, __HIP_MEMORY_SCOPE_AGENT);
    B[3] = __hip_atomic_load(p + 7, __ATOMIC_RELAXED, __HIP_MEMORY_SCOPE_AGENT);
}

// one peer fragment (32B) via 2 L2-coherent loads + drain, single asm statement
#define FLOAD2(ADDR, QA, QB)                                                  \
    asm volatile(                                                             \
        "global_load_dwordx4 %0, %2, off sc0\n\t"                             \
        "global_load_dwordx4 %1, %2, off offset:16 sc0\n\t"                   \
        "s_waitcnt vmcnt(0)"                                                  \
        : "=&v"(QA), "=&v"(QB) : "v"(ADDR) : "memory")

// ---- prep: gate weights [1024 x 320] bf16, frag-major
__global__ void prep_gates(const float* __restrict__ W_ih, const float* __restrict__ W_hh,
                           char* __restrict__ ws) {
    int F = blockIdx.x;
    int T = F / NKC, kc = F - T * NKC;
    int l = threadIdx.x;
    int row  = 16 * T + (l & 15);
    int unit = row >> 2, gt = row & 3;
    int orig = gt * 256 + unit;
    uint32_t w[4];
#pragma unroll
    for (int p = 0; p < 4; ++p) {
        float v[2];
#pragma unroll
        for (int e = 0; e < 2; ++e) {
            int k = 32 * kc + 8 * (l >> 4) + 2 * p + e;
            v[e] = (k < 64) ? W_ih[orig * 67 + 3 + k] : W_hh[orig * 256 + (k - 64)];
        }
        w[p] = (uint32_t)f2bf(v[0]) | ((uint32_t)f2bf(v[1]) << 16);
    }
    *(uint4*)(ws + GOFF + (size_t)F * 1024 + (size_t)l * 16) = make_uint4(w[0], w[1], w[2], w[3]);
}

__global__ void prep_w1(const float* __restrict__ W1, char* __restrict__ ws) {
    int F = blockIdx.x;
    int T = F / 8, kc = F - T * 8;
    int l = threadIdx.x;
    int row = 16 * T + (l & 15);
    uint32_t w[4];
#pragma unroll
    for (int p = 0; p < 4; ++p) {
        int k = 32 * kc + 8 * (l >> 4) + 2 * p;
        w[p] = (uint32_t)f2bf(W1[row * 256 + k]) | ((uint32_t)f2bf(W1[row * 256 + k + 1]) << 16);
    }
    *(uint4*)(ws + W1OFF + (size_t)F * 1024 + (size_t)l * 16) = make_uint4(w[0], w[1], w[2], w[3]);
}

__global__ void prep_small(const float* __restrict__ b_ih, const float* __restrict__ b_hh,
                           char* __restrict__ ws) {
    int t = threadIdx.x;
    float* sb = (float*)(ws + BOFF);
    if (t < 1024) {
        int unit = t >> 2, gt = t & 3;
        int orig = gt * 256 + unit;
        sb[t] = b_ih[orig] + b_hh[orig];
    }
}

// ---- main: 256 blocks (32 groups x 8 slices, XCD-colocated)
//      per-wave single-peer poll -> LDS B-fragment share -> register MFMA
__global__ __launch_bounds__(512, 2) void lstm_main(
        const float* __restrict__ noise, const float* __restrict__ gap,
        const float* __restrict__ W_ih, const float* __restrict__ b1p,
        const float* __restrict__ W2p, const float* __restrict__ b2p,
        char* __restrict__ ws, float* __restrict__ out) {
    __shared__ uint16_t actn[2][16][64];   // noise tile, parity dbuf, XOR-swizzled
    __shared__ uint16_t hfrag[8][512];     // B-fragments: chunk p, (q*16+col)*8 bf16
    __shared__ float dp_part[2][16][9];
    __shared__ float gxy[2][16][2];
    __shared__ int s_gf;

    const int tid  = threadIdx.x;
    const int w    = tid >> 6;
    const int lane = tid & 63;
    const int q    = lane >> 4;
    const int col  = lane & 15;
    // XCD-colocating swizzle: n%8 -> XCD (verified by runtime XCC_ID exchange)
    const int n    = blockIdx.x;
    const int x_   = n & 7, k_ = n >> 3;
    const int g    = x_ * 4 + (k_ & 3);
    const int s    = k_ >> 2;
    const int b0   = g * MB;
    const int swz  = (col & 7) << 3;
    const int myidx = g * 8 + s;
    const int mp   = (s + w) & 7;          // this wave's polled slice (w==0 -> self)

    const uint4* gfr  = (const uint4*)(ws + GOFF);
    const uint4* w1fr = (const uint4*)(ws + W1OFF);
    const float* bias = (const float*)(ws + BOFF);
    uint32_t* ids  = (uint32_t*)(ws + XOFF);
    char*     payF = ws + XOFF + IDSB;
    uint32_t* payS = (uint32_t*)(ws + XOFF + IDSB + PAYB);

    for (int i = tid; i < 8 * 512; i += 512) ((uint16_t*)hfrag)[i] = 0;

    // ---- weights -> VGPRs
    const int T = 8 * s + w;
    uint4 gw[NKC];
#pragma unroll
    for (int kc = 0; kc < NKC; ++kc) gw[kc] = gfr[(size_t)(T * NKC + kc) * 64 + lane];
    uint4 w1w[16];
#pragma unroll
    for (int i = 0; i < 2; ++i)
#pragma unroll
        for (int kc = 0; kc < 8; ++kc)
            w1w[i * 8 + kc] = w1fr[(size_t)((2 * w + i) * 8 + kc) * 64 + lane];

    const int rb = 16 * T + 4 * q;
    const float bI = bias[rb], bF = bias[rb + 1], bG = bias[rb + 2], bO = bias[rb + 3];
    float wx0[4], wx1[4], wx2[4];
#pragma unroll
    for (int r = 0; r < 4; ++r) {
        int row = rb + r;
        int orig = (row & 3) * 256 + (row >> 2);
        wx0[r] = W_ih[orig * 67 + 0];
        wx1[r] = W_ih[orig * 67 + 1];
        wx2[r] = W_ih[orig * 67 + 2] * 24.0f;
    }
    float b1r[8], w2r[8];
#pragma unroll
    for (int a = 0; a < 2; ++a)
#pragma unroll
        for (int r = 0; r < 4; ++r) {
            int row = 32 * w + 16 * a + 4 * q + r;
            b1r[4 * a + r] = b1p[row];
            w2r[4 * a + r] = W2p[row];
        }
    const float b2v = b2p[0];

    // ---- XCC-id exchange -> groupfast (known-good agent path, one-time)
    uint32_t myx;
    asm volatile("s_getreg_b32 %0, hwreg(HW_REG_XCC_ID)" : "=s"(myx));
    if (tid == 0)
        __hip_atomic_store(&ids[myidx], 0x100u | (myx & 0xffu),
                           __ATOMIC_RELAXED, __HIP_MEMORY_SCOPE_AGENT);
    if (tid < 8) {
        uint32_t v;
        do { v = __hip_atomic_load(&ids[g * 8 + tid], __ATOMIC_RELAXED,
                                   __HIP_MEMORY_SCOPE_AGENT); } while (!(v & 0x100u));
        unsigned long long bal = __ballot((v & 0xffu) == (myx & 0xffu));
        if (tid == 0) s_gf = ((bal & 0xffull) == 0xffull) ? 1 : 0;
    }

    // ---- poll/publish addresses
    const uint64_t AFw = (uint64_t)(uintptr_t)(payF + (size_t)(g * 8 + mp) * 4096
                                               + (size_t)(512 * q + 32 * col));
    const int ASWw = (g * 8 + mp) * 1024 + 128 * q + 8 * col;
    const int U = 4 * w + q;                                   // own unit within slice
    const int widx = 128 * (U >> 3) + 8 * col + (U & 7);       // own mailbox word
    const uint64_t WFa = (uint64_t)(uintptr_t)(payF + (size_t)myidx * 4096 + 4 * widx);
    const int WSw = myidx * 1024 + widx;

    // ---- prefetch t=0
    const int nbr = tid >> 5, nj = (tid & 31) * 2;
    const int nsw = (nbr & 7) << 3;
    const float* nptr = noise + (size_t)(b0 + nbr) * TSTEPS * NDIM + nj;
    float2 npf = *(const float2*)nptr;
    const bool xlead = (w == 7 && lane < 16);
    float2 gpf = make_float2(0.f, 0.f);
    if (xlead) gpf = *(const float2*)(gap + (size_t)(b0 + col) * (TSTEPS + 1) * 2);

    float creg = 0.f;
    const f32x4 fz = {0.f, 0.f, 0.f, 0.f};

    __syncthreads();
    bool fm = (s_gf != 0);

#pragma unroll 1
    for (int t = 0; t <= TSTEPS; ++t) {
        const int par = t & 1;
        const uint32_t tg = (uint32_t)t;
        const uint64_t paro = par ? 2048u : 0u;
        const int parw = par << 9;

        // ---- Phase A: stage noise + gxy; poll own peer slice; share via LDS
        if (t < TSTEPS) {
            uint32_t nv = (uint32_t)f2bf(npf.x) | ((uint32_t)f2bf(npf.y) << 16);
            *(uint32_t*)&actn[par][nbr][nj ^ nsw] = nv;
        }
        if (xlead) { gxy[par][col][0] = gpf.x; gxy[par][col][1] = gpf.y; }

        if (t > 0) {
            u32x4v qa, qb;
            bool got = false;
            if (fm) {
                int spins = 0;
                for (;;) {
                    FLOAD2(AFw + paro, qa, qb);
                    if (__all(tagpair_ok(qa, qb, tg))) { got = true; break; }
                    if (++spins > 20000) { fm = false; break; }
                }
            }
            if (!got) {
                do { spoll2(payS + ASWw + parw, qa, qb);
                } while (!__all(tagpair_ok(qa, qb, tg)));
            }
            bf16x8 fr = repack(qa, qb);
            *(uint4*)&hfrag[mp][(q * 16 + col) * 8] = __builtin_bit_cast(uint4, fr);
        }
        // prefetches AFTER the poll so the poll's vmcnt(0) never waits on HBM
        if (t + 1 < TSTEPS) npf = *(const float2*)(nptr + (size_t)(t + 1) * NDIM);
        if (xlead && t < TSTEPS)
            gpf = *(const float2*)(gap + ((size_t)(b0 + col) * (TSTEPS + 1) + (t + 1)) * 2);
        bar_lgkm();

        // ---- Phase B: noise MFMAs (overlap ds_reads) + 8 h-chunks x {gate, head}
        f32x4 h0 = fz, h1 = fz, gacc = fz;
        if (t < TSTEPS) {
            bf16x8 bn0 = *(const bf16x8*)&actn[par][col][(8 * q) ^ swz];
            bf16x8 bn1 = *(const bf16x8*)&actn[par][col][(32 + 8 * q) ^ swz];
            gacc = MFMA16(__builtin_bit_cast(bf16x8, gw[0]), bn0, gacc);
            gacc = MFMA16(__builtin_bit_cast(bf16x8, gw[1]), bn1, gacc);
        }
#pragma unroll
        for (int p = 0; p < 8; ++p) {
            bf16x8 bv = *(const bf16x8*)&hfrag[p][(q * 16 + col) * 8];
            gacc = MFMA16(__builtin_bit_cast(bf16x8, gw[2 + p]), bv, gacc);
            h0   = MFMA16(__builtin_bit_cast(bf16x8, w1w[p]),     bv, h0);
            h1   = MFMA16(__builtin_bit_cast(bf16x8, w1w[8 + p]), bv, h1);
        }
        float part = 0.f;
#pragma unroll
        for (int r = 0; r < 4; ++r) {
            part += ftanh(h0[r] + b1r[r])     * w2r[r];
            part += ftanh(h1[r] + b1r[4 + r]) * w2r[4 + r];
        }
        part += __shfl_xor(part, 16);
        part += __shfl_xor(part, 32);
        if (q == 0) dp_part[par][col][w] = part;
        bar_lgkm();

        // ---- Phase C: dp finalize, out row, gates elementwise, publish h(t+1)
        const float* dpp = &dp_part[par][col][0];
        float inner = b2v + ((dpp[0] + dpp[1]) + (dpp[2] + dpp[3]))
                          + ((dpp[4] + dpp[5]) + (dpp[6] + dpp[7]));
        float tdp = ftanh(inner);
        if (s == 0 && w == 0 && lane < 16) {
            float* o = out + ((size_t)(b0 + col) * (TSTEPS + 1) + t) * 3;
            o[0] = gxy[par][col][0]; o[1] = gxy[par][col][1]; o[2] = 24.0f * tdp;
        }
        if (t == TSTEPS) break;

        const float g0 = gxy[par][col][0], g1 = gxy[par][col][1];
        float ii = gacc[0] + bI + wx0[0] * g0 + wx1[0] * g1 + wx2[0] * tdp;
        float ff = gacc[1] + bF + wx0[1] * g0 + wx1[1] * g1 + wx2[1] * tdp;
        float gg = gacc[2] + bG + wx0[2] * g0 + wx1[2] * g1 + wx2[2] * tdp;
        float oo = gacc[3] + bO + wx0[3] * g0 + wx1[3] * g1 + wx2[3] * tdp;
        float cn = fsig(ff) * creg + fsig(ii) * ftanh(gg);
        creg = cn;
        float hv = fsig(oo) * ftanh(cn);
        uint16_t hb = f2bf(hv);

        // publish (dual store: fast sc0 -> L2, slow agent -> MALL), fire-and-forget
        uint32_t word = ((uint32_t)(t + 1) << 16) | (uint32_t)hb;
        uint64_t wa = WFa + (((t + 1) & 1) ? 2048u : 0u);
        asm volatile("global_store_dword %0, %1, off sc0" :: "v"(wa), "v"(word) : "memory");
        __hip_atomic_store(&payS[WSw + (((t + 1) & 1) << 9)], word,
                           __ATOMIC_RELAXED, __HIP_MEMORY_SCOPE_AGENT);
    }
}

extern "C" void kernel_launch(void* const* d_in, const int* in_sizes, int n_in,
                              void* d_out, int out_size, void* d_ws, size_t ws_size,
                              hipStream_t stream) {
    (void)in_sizes; (void)n_in; (void)out_size;
    if (ws_size < WSNEED) return;  // fail loudly (output stays poisoned)

    const float* noise = (const float*)d_in[0];
    const float* gap   = (const float*)d_in[1];
    const float* W_ih  = (const float*)d_in[2];
    const float* W_hh  = (const float*)d_in[3];
    const float* b_ih  = (const float*)d_in[4];
    const float* b_hh  = (const float*)d_in[5];
    const float* W1    = (const float*)d_in[6];
    const float* b1    = (const float*)d_in[7];
    const float* W2    = (const float*)d_in[8];
    const float* b2    = (const float*)d_in[9];
    char*  ws  = (char*)d_ws;
    float* out = (float*)d_out;

    hipMemsetAsync(ws + XOFF, 0, IDSB + 2 * PAYB, stream);  // ids + both mailboxes
    hipLaunchKernelGGL(prep_gates, dim3(NGT * NKC), dim3(64), 0, stream, W_ih, W_hh, ws);
    hipLaunchKernelGGL(prep_w1,    dim3(16 * 8),    dim3(64), 0, stream, W1, ws);
    hipLaunchKernelGGL(prep_small, dim3(1), dim3(1024), 0, stream, b_ih, b_hh, ws);
    hipLaunchKernelGGL(lstm_main,  dim3(GROUPS * SLICES), dim3(512), 0, stream,
                       noise, gap, W_ih, b1, W2, b2, ws, out);
}

// Round 8
// 6980.960 us; speedup vs baseline: 4.8739x; 4.8739x over previous
//
#include <hip/hip_runtime.h>
#include <stdint.h>
#include <stddef.h>

typedef __bf16 bf16x8 __attribute__((ext_vector_type(8)));
typedef float f32x4 __attribute__((ext_vector_type(4)));

#define MFMA16(a, b, c) __builtin_amdgcn_mfma_f32_16x16x32_bf16((a), (b), (c), 0, 0, 0)

// problem dims
#define TSTEPS 1024
#define NDIM   64
#define NKC    10     // gate K-chunks: 0,1 = noise(64); 2..9 = h chunks of 32
#define NGT    64
#define MB     16
#define GROUPS 32
#define SLICES 4      // blocks per group; each owns 64 hidden units

// workspace layout (bytes)
#define GOFF    ((size_t)0)
#define GBYTES  ((size_t)NGT * NKC * 1024)       // 655360
#define W1OFF   (GOFF + GBYTES)
#define W1BYTES ((size_t)16 * 8 * 1024)          // 131072
#define BOFF    (W1OFF + W1BYTES)                // 1024 f32 reordered gate bias
#define XOFF    (BOFF + 4096)                    // mailbox: 32g*4s*2par*1024 words
#define PAYB    ((size_t)GROUPS * SLICES * 2 * 1024 * 4)   // 1 MiB
#define WSNEED  (XOFF + PAYB)

__device__ __forceinline__ uint16_t f2bf(float f) {
    union { float f; uint32_t u; } v; v.f = f;
    return (uint16_t)((v.u + 0x7FFFu + ((v.u >> 16) & 1u)) >> 16);  // RNE
}
__device__ __forceinline__ float fsig(float x) { return 1.0f / (1.0f + __expf(-x)); }
__device__ __forceinline__ float ftanh(float x) { return 2.0f / (1.0f + __expf(-2.0f * x)) - 1.0f; }

__device__ __forceinline__ void bar_lgkm() {
    asm volatile("s_waitcnt lgkmcnt(0)" ::: "memory");
    __builtin_amdgcn_s_barrier();
    asm volatile("" ::: "memory");
}

// ---- prep: gate weights [1024 x 320] bf16, rows interleaved rho = 4*unit + gate,
//      frag-major: frag F=(T*NKC+kc), lane l holds A[16T+(l&15)][32kc+8*(l>>4)+j]
__global__ void prep_gates(const float* __restrict__ W_ih, const float* __restrict__ W_hh,
                           char* __restrict__ ws) {
    int F = blockIdx.x;
    int T = F / NKC, kc = F - T * NKC;
    int l = threadIdx.x;
    int row  = 16 * T + (l & 15);
    int unit = row >> 2, gt = row & 3;
    int orig = gt * 256 + unit;              // torch gate order i,f,g,o blocks of 256
    uint32_t w[4];
#pragma unroll
    for (int p = 0; p < 4; ++p) {
        float v[2];
#pragma unroll
        for (int e = 0; e < 2; ++e) {
            int k = 32 * kc + 8 * (l >> 4) + 2 * p + e;
            v[e] = (k < 64) ? W_ih[orig * 67 + 3 + k] : W_hh[orig * 256 + (k - 64)];
        }
        w[p] = (uint32_t)f2bf(v[0]) | ((uint32_t)f2bf(v[1]) << 16);
    }
    *(uint4*)(ws + GOFF + (size_t)F * 1024 + (size_t)l * 16) = make_uint4(w[0], w[1], w[2], w[3]);
}

// ---- prep: W1 [256 x 256] bf16, frag-major
__global__ void prep_w1(const float* __restrict__ W1, char* __restrict__ ws) {
    int F = blockIdx.x;
    int T = F / 8, kc = F - T * 8;
    int l = threadIdx.x;
    int row = 16 * T + (l & 15);
    uint32_t w[4];
#pragma unroll
    for (int p = 0; p < 4; ++p) {
        int k = 32 * kc + 8 * (l >> 4) + 2 * p;
        w[p] = (uint32_t)f2bf(W1[row * 256 + k]) | ((uint32_t)f2bf(W1[row * 256 + k + 1]) << 16);
    }
    *(uint4*)(ws + W1OFF + (size_t)F * 1024 + (size_t)l * 16) = make_uint4(w[0], w[1], w[2], w[3]);
}

// ---- prep: reordered gate bias
__global__ void prep_small(const float* __restrict__ b_ih, const float* __restrict__ b_hh,
                           char* __restrict__ ws) {
    int t = threadIdx.x;
    float* sb = (float*)(ws + BOFF);
    if (t < 1024) {
        int unit = t >> 2, gt = t & 3;
        int orig = gt * 256 + unit;
        sb[t] = b_ih[orig] + b_hh[orig];
    }
}

// ---- main: 128 blocks (32 groups x 4 slices), MALL tag-word mailbox (round-4 proven),
//      non-redundant u64-per-peer poll, LDS B-fragment share, 36 MFMA/wave/step
__global__ __launch_bounds__(512, 2) void lstm_main(
        const float* __restrict__ noise, const float* __restrict__ gap,
        const float* __restrict__ W_ih, const float* __restrict__ b1p,
        const float* __restrict__ W2p, const float* __restrict__ b2p,
        char* __restrict__ ws, float* __restrict__ out) {
    __shared__ uint16_t hfrag[2][16 * 256];  // [par][col*256+unit] ^ swz, bf16 h
    __shared__ uint16_t actn[2][16 * 64];    // [par][col*64+k]   ^ swz, bf16 noise
    __shared__ float dp_part[2][16][9];
    __shared__ float gxy[2][16][2];

    const int tid  = threadIdx.x;
    const int w    = tid >> 6;
    const int lane = tid & 63;
    const int q    = lane >> 4;
    const int col  = lane & 15;
    const int n    = blockIdx.x;
    const int g    = n >> 2;                 // group: 4 consecutive blocks -> 4 XCDs
    const int s    = n & 3;
    const int b0   = g * MB;
    const int swz  = (col & 7) << 3;         // element-granular 16B swizzle

    const uint4* gfr  = (const uint4*)(ws + GOFF);
    const uint4* w1fr = (const uint4*)(ws + W1OFF);
    const float* bias = (const float*)(ws + BOFF);
    uint32_t* pay = (uint32_t*)(ws + XOFF);

    for (int i = tid; i < 16 * 256; i += 512) hfrag[0][i] = 0;

    // ---- weights -> VGPRs: gate tiles T0=16s+2w, T0+1 (10 chunks each) + full W1 (2 tiles)
    const int T0 = 16 * s + 2 * w;
    uint4 gw0[NKC], gw1[NKC];
#pragma unroll
    for (int kc = 0; kc < NKC; ++kc) {
        gw0[kc] = gfr[(size_t)(T0 * NKC + kc) * 64 + lane];
        gw1[kc] = gfr[(size_t)((T0 + 1) * NKC + kc) * 64 + lane];
    }
    uint4 w1w[16];
#pragma unroll
    for (int i = 0; i < 2; ++i)
#pragma unroll
        for (int kc = 0; kc < 8; ++kc)
            w1w[i * 8 + kc] = w1fr[(size_t)((2 * w + i) * 8 + kc) * 64 + lane];

    float bb[2][4], wxa[2][4], wxb[2][4], wxc[2][4];
#pragma unroll
    for (int i = 0; i < 2; ++i) {
        int rb = 256 * s + 16 * (2 * w + i) + 4 * q;   // global reordered gate row base
#pragma unroll
        for (int r = 0; r < 4; ++r) {
            int row = rb + r;
            int orig = (row & 3) * 256 + (row >> 2);
            bb[i][r]  = bias[row];
            wxa[i][r] = W_ih[orig * 67 + 0];
            wxb[i][r] = W_ih[orig * 67 + 1];
            wxc[i][r] = W_ih[orig * 67 + 2] * 24.0f;
        }
    }
    float b1r[8], w2r[8];
#pragma unroll
    for (int a = 0; a < 2; ++a)
#pragma unroll
        for (int r = 0; r < 4; ++r) {
            int row = 32 * w + 16 * a + 4 * q + r;
            b1r[4 * a + r] = b1p[row];
            w2r[4 * a + r] = W2p[row];
        }
    const float b2v = b2p[0];

    // ---- mailbox: slot (g*4+slice, par) = 1024 words; word idx = local_unit*16 + col
    int pbase[3], ps[3];
#pragma unroll
    for (int p = 0; p < 3; ++p) {
        ps[p] = (s + 1 + p) & 3;
        pbase[p] = ((g * 4 + ps[p]) * 2) << 10;
    }
    const int mybase = ((g * 4 + s) * 2) << 10;
    const int lu0 = 8 * w + q, lu1 = 8 * w + 4 + q;    // own local units (i=0,1)

    // ---- prefetch t=0
    const int nbr = tid >> 5, nj = (tid & 31) * 2;
    const int nsw = (nbr & 7) << 3;
    const float* nptr = noise + (size_t)(b0 + nbr) * TSTEPS * NDIM + nj;
    float2 npf = *(const float2*)nptr;
    const bool xlead = (w == 7 && lane < 16);
    float2 gpf = make_float2(0.f, 0.f);
    if (xlead) gpf = *(const float2*)(gap + (size_t)(b0 + col) * (TSTEPS + 1) * 2);

    float creg[2] = {0.f, 0.f};
    const f32x4 fz = {0.f, 0.f, 0.f, 0.f};

    __syncthreads();

#pragma unroll 1
    for (int t = 0; t <= TSTEPS; ++t) {
        const int par = t & 1;
        const uint32_t tg = (uint32_t)t;
        const int parw = par << 10;

        // ---- Phase A: stage noise + gxy; poll 3 peers (1 u64 each); scatter to hfrag
        if (t < TSTEPS) {
            uint32_t nv = (uint32_t)f2bf(npf.x) | ((uint32_t)f2bf(npf.y) << 16);
            *(uint32_t*)&actn[par][(nbr * 64 + nj) ^ nsw] = nv;
        }
        if (xlead) {
            gxy[par][col][0] = gpf.x; gxy[par][col][1] = gpf.y;
            if (s == 0) {
                float* o = out + ((size_t)(b0 + col) * (TSTEPS + 1) + t) * 3;
                o[0] = gpf.x; o[1] = gpf.y;
            }
        }
        if (t > 0) {
            unsigned long long pv[3];
            unsigned pend = 0x7;
            do {
#pragma unroll
                for (int p = 0; p < 3; ++p)
                    if (pend & (1u << p)) {
                        unsigned long long v = __hip_atomic_load(
                            (const unsigned long long*)&pay[pbase[p] + parw + 2 * tid],
                            __ATOMIC_RELAXED, __HIP_MEMORY_SCOPE_AGENT);
                        if ((((uint32_t)(v >> 16)) & 0xffffu) == tg &&
                            ((uint32_t)(v >> 48)) == tg) {
                            pv[p] = v; pend &= ~(1u << p);
                        }
                    }
            } while (pend);
            const int ru = tid >> 3;                 // peer local unit
            const int rc0 = 2 * (tid & 7);           // two adjacent cols
#pragma unroll
            for (int p = 0; p < 3; ++p) {
                int gu = 64 * ps[p] + ru;
                hfrag[par][(rc0 * 256 + gu) ^ ((rc0 & 7) << 3)]           = (uint16_t)pv[p];
                hfrag[par][((rc0 + 1) * 256 + gu) ^ (((rc0 + 1) & 7) << 3)] = (uint16_t)(pv[p] >> 32);
            }
        }
        if (t + 1 < TSTEPS) npf = *(const float2*)(nptr + (size_t)(t + 1) * NDIM);
        if (xlead && t < TSTEPS)
            gpf = *(const float2*)(gap + ((size_t)(b0 + col) * (TSTEPS + 1) + (t + 1)) * 2);
        bar_lgkm();

        // ---- Phase B: gates (2 tiles x 10 chunks) + head (16) from LDS B-frags
        f32x4 ga0 = fz, ga1 = fz, h0 = fz, h1 = fz;
        {
            bf16x8 bn0 = *(const bf16x8*)&actn[par][(col * 64 + 8 * q) ^ swz];
            bf16x8 bn1 = *(const bf16x8*)&actn[par][(col * 64 + 32 + 8 * q) ^ swz];
            ga0 = MFMA16(__builtin_bit_cast(bf16x8, gw0[0]), bn0, ga0);
            ga0 = MFMA16(__builtin_bit_cast(bf16x8, gw0[1]), bn1, ga0);
            ga1 = MFMA16(__builtin_bit_cast(bf16x8, gw1[0]), bn0, ga1);
            ga1 = MFMA16(__builtin_bit_cast(bf16x8, gw1[1]), bn1, ga1);
        }
#pragma unroll
        for (int c = 0; c < 8; ++c) {
            bf16x8 bv = *(const bf16x8*)&hfrag[par][(col * 256 + 32 * c + 8 * q) ^ swz];
            ga0 = MFMA16(__builtin_bit_cast(bf16x8, gw0[2 + c]), bv, ga0);
            ga1 = MFMA16(__builtin_bit_cast(bf16x8, gw1[2 + c]), bv, ga1);
            h0  = MFMA16(__builtin_bit_cast(bf16x8, w1w[c]),     bv, h0);
            h1  = MFMA16(__builtin_bit_cast(bf16x8, w1w[8 + c]), bv, h1);
        }
        float part = 0.f;
#pragma unroll
        for (int r = 0; r < 4; ++r) {
            part += ftanh(h0[r] + b1r[r])     * w2r[r];
            part += ftanh(h1[r] + b1r[4 + r]) * w2r[4 + r];
        }
        part += __shfl_xor(part, 16);
        part += __shfl_xor(part, 32);
        if (q == 0) dp_part[par][col][w] = part;
        bar_lgkm();

        // ---- Phase C: dp finalize (all lanes), out col2, elementwise, publish h(t+1)
        const float* dpp = &dp_part[par][col][0];
        float inner = b2v + ((dpp[0] + dpp[1]) + (dpp[2] + dpp[3]))
                          + ((dpp[4] + dpp[5]) + (dpp[6] + dpp[7]));
        float tdp = ftanh(inner);
        if (s == 0 && w == 0 && lane < 16)
            out[((size_t)(b0 + col) * (TSTEPS + 1) + t) * 3 + 2] = 24.0f * tdp;
        if (t == TSTEPS) break;

        const float g0 = gxy[par][col][0], g1 = gxy[par][col][1];
        const int npar = (t + 1) & 1;
        const uint32_t ntag = (uint32_t)(t + 1) << 16;
#pragma unroll
        for (int i = 0; i < 2; ++i) {
            const f32x4& ga = i ? ga1 : ga0;
            float ii = ga[0] + bb[i][0] + wxa[i][0] * g0 + wxb[i][0] * g1 + wxc[i][0] * tdp;
            float ff = ga[1] + bb[i][1] + wxa[i][1] * g0 + wxb[i][1] * g1 + wxc[i][1] * tdp;
            float gg = ga[2] + bb[i][2] + wxa[i][2] * g0 + wxb[i][2] * g1 + wxc[i][2] * tdp;
            float oo = ga[3] + bb[i][3] + wxa[i][3] * g0 + wxb[i][3] * g1 + wxc[i][3] * tdp;
            float cn = fsig(ff) * creg[i] + fsig(ii) * ftanh(gg);
            creg[i] = cn;
            float hv = fsig(oo) * ftanh(cn);
            uint16_t hb = f2bf(hv);
            int lu = i ? lu1 : lu0;
            __hip_atomic_store(&pay[mybase + (npar << 10) + lu * 16 + col],
                               ntag | (uint32_t)hb,
                               __ATOMIC_RELAXED, __HIP_MEMORY_SCOPE_AGENT);
            hfrag[npar][(col * 256 + 64 * s + lu) ^ swz] = hb;
        }
    }
}

extern "C" void kernel_launch(void* const* d_in, const int* in_sizes, int n_in,
                              void* d_out, int out_size, void* d_ws, size_t ws_size,
                              hipStream_t stream) {
    (void)in_sizes; (void)n_in; (void)out_size;
    if (ws_size < WSNEED) return;  // fail loudly (output stays poisoned)

    const float* noise = (const float*)d_in[0];
    const float* gap   = (const float*)d_in[1];
    const float* W_ih  = (const float*)d_in[2];
    const float* W_hh  = (const float*)d_in[3];
    const float* b_ih  = (const float*)d_in[4];
    const float* b_hh  = (const float*)d_in[5];
    const float* W1    = (const float*)d_in[6];
    const float* b1    = (const float*)d_in[7];
    const float* W2    = (const float*)d_in[8];
    const float* b2    = (const float*)d_in[9];
    char*  ws  = (char*)d_ws;
    float* out = (float*)d_out;

    hipMemsetAsync(ws + XOFF, 0, PAYB, stream);   // mailbox tags -> 0 (replay-safe)
    hipLaunchKernelGGL(prep_gates, dim3(NGT * NKC), dim3(64), 0, stream, W_ih, W_hh, ws);
    hipLaunchKernelGGL(prep_w1,    dim3(16 * 8),    dim3(64), 0, stream, W1, ws);
    hipLaunchKernelGGL(prep_small, dim3(1), dim3(1024), 0, stream, b_ih, b_hh, ws);
    hipLaunchKernelGGL(lstm_main,  dim3(GROUPS * SLICES), dim3(512), 0, stream,
                       noise, gap, W_ih, b1, W2, b2, ws, out);
}

// Round 9
// 3136.498 us; speedup vs baseline: 10.8478x; 2.2257x over previous
//
#include <hip/hip_runtime.h>
#include <stdint.h>
#include <stddef.h>

typedef __bf16 bf16x8 __attribute__((ext_vector_type(8)));
typedef float f32x4 __attribute__((ext_vector_type(4)));

#define MFMA16(a, b, c) __builtin_amdgcn_mfma_f32_16x16x32_bf16((a), (b), (c), 0, 0, 0)

// problem dims
#define TSTEPS 1024
#define NDIM   64
#define NKC    10     // K = 320: 0..63 noise | 64..319 h  (x-cols handled in VALU)
#define NGT    64
#define MB     16
#define GROUPS 32
#define SLICES 8

// workspace layout (bytes)
#define GOFF    ((size_t)0)
#define GBYTES  ((size_t)NGT * NKC * 1024)       // 655360
#define W1OFF   (GOFF + GBYTES)
#define W1BYTES ((size_t)16 * 8 * 1024)          // 131072
#define BOFF    (W1OFF + W1BYTES)                // 1024 f32 reordered gate bias
#define XOFF    (BOFF + 4096)                    // mailbox: 256 slices * 2 parity * 512 u32
#define XBYTES  ((size_t)256 * 2 * 512 * 4)      // 1 MiB
#define WSNEED  (XOFF + XBYTES)

__device__ __forceinline__ uint16_t f2bf(float f) {
    union { float f; uint32_t u; } v; v.f = f;
    return (uint16_t)((v.u + 0x7FFFu + ((v.u >> 16) & 1u)) >> 16);  // RNE
}
__device__ __forceinline__ float fsig(float x) { return 1.0f / (1.0f + __expf(-x)); }
__device__ __forceinline__ float ftanh(float x) { return 2.0f / (1.0f + __expf(-2.0f * x)) - 1.0f; }

// lgkmcnt-only barrier: does NOT drain vmcnt
__device__ __forceinline__ void bar_lgkm() {
    asm volatile("s_waitcnt lgkmcnt(0)" ::: "memory");
    __builtin_amdgcn_s_barrier();
    asm volatile("" ::: "memory");
}

// ---- prep: gate weights [1024 x 320] bf16, rows interleaved rho = 4*unit + gate,
//      frag-major: frag F=(T*NKC+kc), lane l holds A[16T+(l&15)][32kc+8*(l>>4)+j]
//      k map: 0..63 -> noise (W_ih cols 3..66); 64..319 -> h (W_hh)
__global__ void prep_gates(const float* __restrict__ W_ih, const float* __restrict__ W_hh,
                           char* __restrict__ ws) {
    int F = blockIdx.x;
    int T = F / NKC, kc = F - T * NKC;
    int l = threadIdx.x;
    int row  = 16 * T + (l & 15);
    int unit = row >> 2, gt = row & 3;
    int orig = gt * 256 + unit;              // torch gate order i,f,g,o blocks of 256
    uint32_t w[4];
#pragma unroll
    for (int p = 0; p < 4; ++p) {
        float v[2];
#pragma unroll
        for (int e = 0; e < 2; ++e) {
            int k = 32 * kc + 8 * (l >> 4) + 2 * p + e;
            v[e] = (k < 64) ? W_ih[orig * 67 + 3 + k] : W_hh[orig * 256 + (k - 64)];
        }
        w[p] = (uint32_t)f2bf(v[0]) | ((uint32_t)f2bf(v[1]) << 16);
    }
    *(uint4*)(ws + GOFF + (size_t)F * 1024 + (size_t)l * 16) = make_uint4(w[0], w[1], w[2], w[3]);
}

// ---- prep: W1 [256 x 256] bf16, frag-major
__global__ void prep_w1(const float* __restrict__ W1, char* __restrict__ ws) {
    int F = blockIdx.x;
    int T = F / 8, kc = F - T * 8;
    int l = threadIdx.x;
    int row = 16 * T + (l & 15);
    uint32_t w[4];
#pragma unroll
    for (int p = 0; p < 4; ++p) {
        int k = 32 * kc + 8 * (l >> 4) + 2 * p;
        w[p] = (uint32_t)f2bf(W1[row * 256 + k]) | ((uint32_t)f2bf(W1[row * 256 + k + 1]) << 16);
    }
    *(uint4*)(ws + W1OFF + (size_t)F * 1024 + (size_t)l * 16) = make_uint4(w[0], w[1], w[2], w[3]);
}

// ---- prep: reordered gate bias
__global__ void prep_small(const float* __restrict__ b_ih, const float* __restrict__ b_hh,
                           char* __restrict__ ws) {
    int t = threadIdx.x;
    float* sb = (float*)(ws + BOFF);
    if (t < 1024) {
        int unit = t >> 2, gt = t & 3;
        int orig = gt * 256 + unit;
        sb[t] = b_ih[orig] + b_hh[orig];
    }
}

// ---- main: 256 blocks (32 groups x 8 slices), weights in VGPRs,
//      tag-in-payload mailbox (R4-proven), gates+head overlapped in phase B,
//      out-writes deferred past the next poll (vmcnt decoupling)
__global__ __launch_bounds__(512, 2) void lstm_main(
        const float* __restrict__ noise, const float* __restrict__ gap,
        const float* __restrict__ W_ih, const float* __restrict__ b1p,
        const float* __restrict__ W2p, const float* __restrict__ b2p,
        char* __restrict__ ws, float* __restrict__ out) {
    __shared__ uint16_t act[MB * 320];   // [batch][k], XOR-swizzled, bf16; h at 64..319
    __shared__ float dp_part[16][9];     // padded: conflict-free
    __shared__ float gxy[2][16][2];      // parity-doubled gap staging

    const int tid  = threadIdx.x;
    const int w    = tid >> 6;
    const int lane = tid & 63;
    const int q    = lane >> 4;
    const int col  = lane & 15;
    const int g    = blockIdx.x >> 3;
    const int s    = blockIdx.x & 7;
    const int b0   = g * MB;
    const int swz  = (col & 7) << 3;

    const uint4* gfr  = (const uint4*)(ws + GOFF);
    const uint4* w1fr = (const uint4*)(ws + W1OFF);
    const float* bias = (const float*)(ws + BOFF);
    uint32_t* pay = (uint32_t*)(ws + XOFF);

    for (int i = tid; i < MB * 320; i += 512) act[i] = 0;

    // ---- weights -> VGPRs
    const int T = 8 * s + w;             // this wave's gate row-tile (global)
    uint4 gw[NKC];
#pragma unroll
    for (int kc = 0; kc < NKC; ++kc) gw[kc] = gfr[(size_t)(T * NKC + kc) * 64 + lane];
    uint4 w1w[16];                        // full W1: wave w holds head row-tiles 2w, 2w+1
#pragma unroll
    for (int i = 0; i < 2; ++i)
#pragma unroll
        for (int kc = 0; kc < 8; ++kc)
            w1w[i * 8 + kc] = w1fr[(size_t)((2 * w + i) * 8 + kc) * 64 + lane];

    const int rb = 16 * T + 4 * q;
    const float bI = bias[rb], bF = bias[rb + 1], bG = bias[rb + 2], bO = bias[rb + 3];
    float wx0[4], wx1[4], wx2[4];        // f32 x-column weights (rank-3 VALU path)
#pragma unroll
    for (int r = 0; r < 4; ++r) {
        int row = rb + r;
        int orig = (row & 3) * 256 + (row >> 2);
        wx0[r] = W_ih[orig * 67 + 0];
        wx1[r] = W_ih[orig * 67 + 1];
        wx2[r] = W_ih[orig * 67 + 2] * 24.0f;
    }
    float b1r[8], w2r[8];
#pragma unroll
    for (int a = 0; a < 2; ++a)
#pragma unroll
        for (int r = 0; r < 4; ++r) {
            int row = 32 * w + 16 * a + 4 * q + r;
            b1r[4 * a + r] = b1p[row];
            w2r[4 * a + r] = W2p[row];
        }
    const float b2v = b2p[0];

    // ---- prefetch t=0
    const int nbr = tid >> 5, nj = (tid & 31) * 2;
    const float* nptr = noise + (size_t)(b0 + nbr) * TSTEPS * NDIM + nj;
    float2 npf = *(const float2*)nptr;
    const bool xlead = (w == 7 && lane < 16);
    const bool olead = (s == 0 && w == 0);   // q-varying lanes write out rows
    float2 gpf = make_float2(0.f, 0.f);
    if (xlead) gpf = *(const float2*)(gap + (size_t)(b0 + col) * (TSTEPS + 1) * 2);

    float creg = 0.f;
    float o_g0 = 0.f, o_g1 = 0.f, o_tdp = 0.f;   // deferred out payload (step t-1)
    const f32x4 fz = {0.f, 0.f, 0.f, 0.f};
    const int myidx = g * 8 + s;
    const int myunit = 32 * s + 4 * w + q;

    __syncthreads();

#pragma unroll 1
    for (int t = 0; t <= TSTEPS; ++t) {
        const int par = t & 1;
        const uint32_t tg = (uint32_t)t;

        // ---- Phase A: stage noise + gxy; poll 7 peers; deferred out write; prefetch
        if (t < TSTEPS) {
            uint32_t nv = (uint32_t)f2bf(npf.x) | ((uint32_t)f2bf(npf.y) << 16);
            int sw = (nbr & 7) << 3;
            *(uint32_t*)&act[nbr * 320 + (nj ^ sw)] = nv;
        }
        if (xlead) { gxy[par][col][0] = gpf.x; gxy[par][col][1] = gpf.y; }

        if (t > 0) {   // receive 7 peer h-slices: tag match == data valid
            unsigned pend = 0x7f;
            uint32_t vv[7];
            do {
#pragma unroll
                for (int pi = 0; pi < 7; ++pi)
                    if (pend & (1u << pi)) {
                        int p = (s + 1 + pi) & 7;
                        vv[pi] = __hip_atomic_load(
                            &pay[(((g * 8 + p) * 2 + par) << 9) + 64 * w + lane],
                            __ATOMIC_RELAXED, __HIP_MEMORY_SCOPE_AGENT);
                    }
#pragma unroll
                for (int pi = 0; pi < 7; ++pi)
                    if ((pend & (1u << pi)) && (vv[pi] >> 16) == tg) {
                        int p = (s + 1 + pi) & 7;
                        int u = 32 * p + 4 * w + q;
                        act[col * 320 + ((64 + u) ^ swz)] = (uint16_t)vv[pi];
                        pend &= ~(1u << pi);
                    }
            } while (pend);
            // deferred out row (t-1): HBM stores drain during bar+B, not in next poll
            if (olead && q == 0) {
                float* o = out + ((size_t)(b0 + col) * (TSTEPS + 1) + (t - 1)) * 3;
                o[0] = o_g0; o[1] = o_g1; o[2] = 24.0f * o_tdp;
            }
        }
        // prefetches AFTER the poll so the poll's waits never cover HBM loads
        if (t + 1 < TSTEPS) npf = *(const float2*)(nptr + (size_t)(t + 1) * NDIM);
        if (xlead && t < TSTEPS)
            gpf = *(const float2*)(gap + ((size_t)(b0 + col) * (TSTEPS + 1) + (t + 1)) * 2);
        bar_lgkm();

        // ---- Phase B: gates (noise+h) and head overlapped, shared LDS reads
        f32x4 h0 = fz, h1 = fz, ga = fz;
        {
            bf16x8 bn0 = *(const bf16x8*)&act[col * 320 + ((8 * q) ^ swz)];
            bf16x8 bn1 = *(const bf16x8*)&act[col * 320 + ((32 + 8 * q) ^ swz)];
            ga = MFMA16(__builtin_bit_cast(bf16x8, gw[0]), bn0, ga);
            ga = MFMA16(__builtin_bit_cast(bf16x8, gw[1]), bn1, ga);
        }
#pragma unroll
        for (int kc = 0; kc < 8; ++kc) {
            bf16x8 bv = *(const bf16x8*)&act[col * 320 + ((64 + 32 * kc + 8 * q) ^ swz)];
            ga = MFMA16(__builtin_bit_cast(bf16x8, gw[2 + kc]), bv, ga);
            h0 = MFMA16(__builtin_bit_cast(bf16x8, w1w[kc]),     bv, h0);
            h1 = MFMA16(__builtin_bit_cast(bf16x8, w1w[8 + kc]), bv, h1);
        }
        float part = 0.f;
#pragma unroll
        for (int r = 0; r < 4; ++r) {
            part += ftanh(h0[r] + b1r[r])     * w2r[r];
            part += ftanh(h1[r] + b1r[4 + r]) * w2r[4 + r];
        }
        part += __shfl_xor(part, 16);
        part += __shfl_xor(part, 32);
        if (q == 0) dp_part[col][w] = part;
        bar_lgkm();

        // ---- Phase C: dp finalize, elementwise, publish (LDS writes last)
        const float* dpp = &dp_part[col][0];
        float inner = b2v + ((dpp[0] + dpp[1]) + (dpp[2] + dpp[3]))
                          + ((dpp[4] + dpp[5]) + (dpp[6] + dpp[7]));
        float tdp = ftanh(inner);
        const float g0 = gxy[par][col][0], g1 = gxy[par][col][1];
        o_g0 = g0; o_g1 = g1; o_tdp = tdp;

        if (t == TSTEPS) {
            if (olead && q == 0) {   // final row: no next phase A, write now
                float* o = out + ((size_t)(b0 + col) * (TSTEPS + 1) + t) * 3;
                o[0] = g0; o[1] = g1; o[2] = 24.0f * tdp;
            }
            break;
        }

        float ii = ga[0] + bI + wx0[0] * g0 + wx1[0] * g1 + wx2[0] * tdp;
        float ff = ga[1] + bF + wx0[1] * g0 + wx1[1] * g1 + wx2[1] * tdp;
        float gg = ga[2] + bG + wx0[2] * g0 + wx1[2] * g1 + wx2[2] * tdp;
        float oo = ga[3] + bO + wx0[3] * g0 + wx1[3] * g1 + wx2[3] * tdp;
        float cn = fsig(ff) * creg + fsig(ii) * ftanh(gg);
        creg = cn;
        float hv = fsig(oo) * ftanh(cn);
        uint16_t hb = f2bf(hv);
        // publish first (fire-and-forget tagged word, tag = t+1), LDS write after
        __hip_atomic_store(&pay[((myidx * 2 + ((t + 1) & 1)) << 9) + 64 * w + lane],
                           ((uint32_t)(t + 1) << 16) | (uint32_t)hb,
                           __ATOMIC_RELAXED, __HIP_MEMORY_SCOPE_AGENT);
        act[col * 320 + ((64 + myunit) ^ swz)] = hb;
    }
}

extern "C" void kernel_launch(void* const* d_in, const int* in_sizes, int n_in,
                              void* d_out, int out_size, void* d_ws, size_t ws_size,
                              hipStream_t stream) {
    (void)in_sizes; (void)n_in; (void)out_size;
    if (ws_size < WSNEED) return;  // fail loudly (output stays poisoned)

    const float* noise = (const float*)d_in[0];
    const float* gap   = (const float*)d_in[1];
    const float* W_ih  = (const float*)d_in[2];
    const float* W_hh  = (const float*)d_in[3];
    const float* b_ih  = (const float*)d_in[4];
    const float* b_hh  = (const float*)d_in[5];
    const float* W1    = (const float*)d_in[6];
    const float* b1    = (const float*)d_in[7];
    const float* W2    = (const float*)d_in[8];
    const float* b2    = (const float*)d_in[9];
    char*  ws  = (char*)d_ws;
    float* out = (float*)d_out;

    hipMemsetAsync(ws + XOFF, 0, XBYTES, stream);   // mailbox tags -> 0 (replay-safe)
    hipLaunchKernelGGL(prep_gates, dim3(NGT * NKC), dim3(64), 0, stream, W_ih, W_hh, ws);
    hipLaunchKernelGGL(prep_w1,    dim3(16 * 8),    dim3(64), 0, stream, W1, ws);
    hipLaunchKernelGGL(prep_small, dim3(1), dim3(1024), 0, stream, b_ih, b_hh, ws);
    hipLaunchKernelGGL(lstm_main,  dim3(GROUPS * SLICES), dim3(512), 0, stream,
                       noise, gap, W_ih, b1, W2, b2, ws, out);
}